// Round 1
// baseline (431.771 us; speedup 1.0000x reference)
//
#include <hip/hip_runtime.h>

#define BATCH 262144
#define EMB 300
#define VOC 100000
#define NBLK 4096
#define WPB 4
// 16 lanes per pair, 4 pair-groups per wave, 4 steps => 16 pairs/wave
// NBLK * WPB * 16 == BATCH

// ---- locality sort parameters ----
#define BSHIFT 7
#define NBUCKET ((VOC + (1 << BSHIFT) - 1) >> BSHIFT)   // 782 buckets of 128 rows

// ---- workspace layout (bytes) ----
#define WS_BLOCKSUMS 0                       // 4096 floats = 16384
#define WS_HIST      16384                   // 1024 ints   = 4096 (782 used)
#define WS_OFFS      20480                   // 1024 ints   = 4096
#define WS_PERM      24576                   // BATCH ints  = 1048576
#define WS_PLOSS     (24576 + 1048576)       // BATCH floats= 1048576
#define WS_NEED      (WS_PLOSS + 1048576)    // ~2.02 MB

// ------------------------------------------------------------------
// Sort pass 1: bucket histogram (262144 atomics over 782 counters)
// ------------------------------------------------------------------
__global__ __launch_bounds__(256) void glove_hist(
    const int* __restrict__ center, int* __restrict__ hist)
{
    const int i = blockIdx.x * 256 + threadIdx.x;
    atomicAdd(&hist[center[i] >> BSHIFT], 1);
}

// ------------------------------------------------------------------
// Sort pass 2: exclusive scan of 782 bucket counts (single block)
// ------------------------------------------------------------------
__global__ __launch_bounds__(1024) void glove_scan(
    const int* __restrict__ hist, int* __restrict__ offs)
{
    const int t = threadIdx.x;
    int v = (t < NBUCKET) ? hist[t] : 0;
    const int orig = v;

    // inclusive scan within each 64-lane wave
    #pragma unroll
    for (int off = 1; off < 64; off <<= 1) {
        int n = __shfl_up(v, off, 64);
        if ((t & 63) >= off) v += n;
    }
    __shared__ int wsums[16];
    if ((t & 63) == 63) wsums[t >> 6] = v;
    __syncthreads();
    if (t < 16) {
        int w = wsums[t];
        #pragma unroll
        for (int off = 1; off < 16; off <<= 1) {
            int n = __shfl_up(w, off, 16);
            if (t >= off) w += n;
        }
        wsums[t] = w;
    }
    __syncthreads();
    const int add = (t >= 64) ? wsums[(t >> 6) - 1] : 0;
    if (t < NBUCKET) offs[t] = (v + add) - orig;   // exclusive prefix
}

// ------------------------------------------------------------------
// Sort pass 3: scatter pair ids into bucket-ordered perm[]
// (slot order within a bucket is nondeterministic; harmless — the
//  final reduction re-reads pair_loss in ORIGINAL pair order)
// ------------------------------------------------------------------
__global__ __launch_bounds__(256) void glove_scatter(
    const int* __restrict__ center, int* __restrict__ offs,
    int* __restrict__ perm)
{
    const int i = blockIdx.x * 256 + threadIdx.x;
    const int b = center[i] >> BSHIFT;
    const int slot = atomicAdd(&offs[b], 1);
    perm[slot] = i;
}

// ------------------------------------------------------------------
// Main gather+dot kernel, processing pairs in perm order.
// Inner arithmetic is IDENTICAL to the verified baseline kernel;
// result for each pair is scatter-written to pair_loss[orig_id].
// ------------------------------------------------------------------
__global__ __launch_bounds__(256) void glove_main_perm(
    const int*   __restrict__ perm,
    const int*   __restrict__ center,
    const int*   __restrict__ outside,
    const float* __restrict__ coocs,
    const float* __restrict__ weighting,
    const float* __restrict__ cemb,
    const float* __restrict__ oemb,
    const float* __restrict__ cbias,
    const float* __restrict__ obias,
    float*       __restrict__ pair_loss)
{
    const int tid  = threadIdx.x;
    const int warp = tid >> 6;
    const int lane = tid & 63;
    const int l    = lane & 15;   // lane within 16-lane pair-group
    const int g    = lane >> 4;   // pair-group 0..3
    const int base = (blockIdx.x * WPB + warp) * 16 + g;

    int pp[4];
    #pragma unroll
    for (int it = 0; it < 4; ++it) pp[it] = perm[base + it * 4];

    int ci[4], oi[4];
    #pragma unroll
    for (int it = 0; it < 4; ++it) {
        ci[it] = center[pp[it]];
        oi[it] = outside[pp[it]];
    }

    // double-buffered stage registers
    float4 sa[2][5], sb[2][5];
    float  scb[2], sob[2], scc[2], swt[2];

    // ---- prologue: load stages 0 and 1 ----
    #pragma unroll
    for (int s = 0; s < 2; ++s) {
        const float4* __restrict__ A = (const float4*)(cemb + (long)ci[s] * EMB);
        const float4* __restrict__ B = (const float4*)(oemb + (long)oi[s] * EMB);
        #pragma unroll
        for (int i = 0; i < 4; ++i) {
            sa[s][i] = A[i * 16 + l];
            sb[s][i] = B[i * 16 + l];
        }
        sa[s][4].x = 0.f; sa[s][4].y = 0.f; sa[s][4].z = 0.f; sa[s][4].w = 0.f;
        sb[s][4] = sa[s][4];
        if (l < 11) {               // 75 float4/row: lanes 0..10 cover [64,75)
            sa[s][4] = A[64 + l];
            sb[s][4] = B[64 + l];
        }
        scb[s] = cbias[ci[s]];
        sob[s] = obias[oi[s]];
        scc[s] = coocs[pp[s]];
        swt[s] = weighting[pp[s]];
    }

    // ---- pipelined main: compute stage it from buf, refill buf with it+2 ----
    #pragma unroll
    for (int it = 0; it < 4; ++it) {
        const int buf = it & 1;

        float s = 0.f;
        #pragma unroll
        for (int i = 0; i < 5; ++i) {
            s += sa[buf][i].x * sb[buf][i].x + sa[buf][i].y * sb[buf][i].y
               + sa[buf][i].z * sb[buf][i].z + sa[buf][i].w * sb[buf][i].w;
        }
        const float cbv = scb[buf], obv = sob[buf], ccv = scc[buf], wtv = swt[buf];

        if (it + 2 < 4) {
            const int n = it + 2;
            const float4* __restrict__ A = (const float4*)(cemb + (long)ci[n] * EMB);
            const float4* __restrict__ B = (const float4*)(oemb + (long)oi[n] * EMB);
            #pragma unroll
            for (int i = 0; i < 4; ++i) {
                sa[buf][i] = A[i * 16 + l];
                sb[buf][i] = B[i * 16 + l];
            }
            if (l < 11) {
                sa[buf][4] = A[64 + l];
                sb[buf][4] = B[64 + l];
            } else {
                sa[buf][4].x = 0.f; sa[buf][4].y = 0.f; sa[buf][4].z = 0.f; sa[buf][4].w = 0.f;
                sb[buf][4] = sa[buf][4];
            }
            scb[buf] = cbias[ci[n]];
            sob[buf] = obias[oi[n]];
            scc[buf] = coocs[pp[n]];
            swt[buf] = weighting[pp[n]];
        }

        // 4-step butterfly within the 16-lane group
        s += __shfl_xor(s, 1);
        s += __shfl_xor(s, 2);
        s += __shfl_xor(s, 4);
        s += __shfl_xor(s, 8);

        if (l == 0) {
            const float e = s + cbv + obv - ccv;
            pair_loss[pp[it]] = wtv * e * e;
        }
    }
}

// ------------------------------------------------------------------
// Re-read pair_loss in ORIGINAL pair order with the ORIGINAL
// reduction tree -> block_sums bit-identical to the baseline kernel.
// ------------------------------------------------------------------
__global__ __launch_bounds__(256) void glove_sum(
    const float* __restrict__ pair_loss, float* __restrict__ block_sums)
{
    const int tid  = threadIdx.x;
    const int warp = tid >> 6;
    const int lane = tid & 63;
    const int l    = lane & 15;
    const int g    = lane >> 4;
    const int base = (blockIdx.x * WPB + warp) * 16 + g;

    float local = 0.0f;
    if (l == 0) {
        #pragma unroll
        for (int it = 0; it < 4; ++it)
            local += pair_loss[base + it * 4];
    }
    local += __shfl_down(local, 32, 64);
    local += __shfl_down(local, 16, 64);

    __shared__ float smem[WPB];
    if (lane == 0) smem[warp] = local;
    __syncthreads();
    if (tid == 0)
        block_sums[blockIdx.x] = smem[0] + smem[1] + smem[2] + smem[3];
}

// ------------------------------------------------------------------
// Baseline main kernel kept verbatim as a fallback if ws is too small
// ------------------------------------------------------------------
__global__ __launch_bounds__(256) void glove_main(
    const int*   __restrict__ center,
    const int*   __restrict__ outside,
    const float* __restrict__ coocs,
    const float* __restrict__ weighting,
    const float* __restrict__ cemb,
    const float* __restrict__ oemb,
    const float* __restrict__ cbias,
    const float* __restrict__ obias,
    float*       __restrict__ block_sums)
{
    const int tid  = threadIdx.x;
    const int warp = tid >> 6;
    const int lane = tid & 63;
    const int l    = lane & 15;
    const int g    = lane >> 4;
    const int base = (blockIdx.x * WPB + warp) * 16 + g;

    int ci[4], oi[4];
    #pragma unroll
    for (int it = 0; it < 4; ++it) {
        ci[it] = center[base + it * 4];
        oi[it] = outside[base + it * 4];
    }

    float4 sa[2][5], sb[2][5];
    float  scb[2], sob[2], scc[2], swt[2];

    #pragma unroll
    for (int s = 0; s < 2; ++s) {
        const float4* __restrict__ A = (const float4*)(cemb + (long)ci[s] * EMB);
        const float4* __restrict__ B = (const float4*)(oemb + (long)oi[s] * EMB);
        #pragma unroll
        for (int i = 0; i < 4; ++i) {
            sa[s][i] = A[i * 16 + l];
            sb[s][i] = B[i * 16 + l];
        }
        sa[s][4].x = 0.f; sa[s][4].y = 0.f; sa[s][4].z = 0.f; sa[s][4].w = 0.f;
        sb[s][4] = sa[s][4];
        if (l < 11) {
            sa[s][4] = A[64 + l];
            sb[s][4] = B[64 + l];
        }
        scb[s] = cbias[ci[s]];
        sob[s] = obias[oi[s]];
        scc[s] = coocs[base + s * 4];
        swt[s] = weighting[base + s * 4];
    }

    float local = 0.0f;

    #pragma unroll
    for (int it = 0; it < 4; ++it) {
        const int buf = it & 1;

        float s = 0.f;
        #pragma unroll
        for (int i = 0; i < 5; ++i) {
            s += sa[buf][i].x * sb[buf][i].x + sa[buf][i].y * sb[buf][i].y
               + sa[buf][i].z * sb[buf][i].z + sa[buf][i].w * sb[buf][i].w;
        }
        const float cbv = scb[buf], obv = sob[buf], ccv = scc[buf], wtv = swt[buf];

        if (it + 2 < 4) {
            const int n = it + 2;
            const float4* __restrict__ A = (const float4*)(cemb + (long)ci[n] * EMB);
            const float4* __restrict__ B = (const float4*)(oemb + (long)oi[n] * EMB);
            #pragma unroll
            for (int i = 0; i < 4; ++i) {
                sa[buf][i] = A[i * 16 + l];
                sb[buf][i] = B[i * 16 + l];
            }
            if (l < 11) {
                sa[buf][4] = A[64 + l];
                sb[buf][4] = B[64 + l];
            } else {
                sa[buf][4].x = 0.f; sa[buf][4].y = 0.f; sa[buf][4].z = 0.f; sa[buf][4].w = 0.f;
                sb[buf][4] = sa[buf][4];
            }
            scb[buf] = cbias[ci[n]];
            sob[buf] = obias[oi[n]];
            scc[buf] = coocs[base + n * 4];
            swt[buf] = weighting[base + n * 4];
        }

        s += __shfl_xor(s, 1);
        s += __shfl_xor(s, 2);
        s += __shfl_xor(s, 4);
        s += __shfl_xor(s, 8);

        if (l == 0) {
            const float e = s + cbv + obv - ccv;
            local += wtv * e * e;
        }
    }

    local += __shfl_down(local, 32, 64);
    local += __shfl_down(local, 16, 64);

    __shared__ float smem[WPB];
    if (lane == 0) smem[warp] = local;
    __syncthreads();
    if (tid == 0)
        block_sums[blockIdx.x] = smem[0] + smem[1] + smem[2] + smem[3];
}

__global__ __launch_bounds__(1024) void glove_reduce(
    const float* __restrict__ part, float* __restrict__ out)
{
    const int t = threadIdx.x;
    float4 v = ((const float4*)part)[t];          // 1024 x 4 = 4096 partials
    float s = v.x + v.y + v.z + v.w;
    #pragma unroll
    for (int off = 32; off > 0; off >>= 1)
        s += __shfl_down(s, off, 64);
    __shared__ float sm[16];
    if ((t & 63) == 0) sm[t >> 6] = s;
    __syncthreads();
    if (t < 16) {
        float x = sm[t];
        #pragma unroll
        for (int off = 8; off > 0; off >>= 1)
            x += __shfl_down(x, off, 16);
        if (t == 0) out[0] = x;
    }
}

extern "C" void kernel_launch(void* const* d_in, const int* in_sizes, int n_in,
                              void* d_out, int out_size, void* d_ws, size_t ws_size,
                              hipStream_t stream) {
    const int*   center    = (const int*)  d_in[0];
    const int*   outside   = (const int*)  d_in[1];
    const float* coocs     = (const float*)d_in[2];
    const float* weighting = (const float*)d_in[3];
    const float* cemb      = (const float*)d_in[4];
    const float* oemb      = (const float*)d_in[5];
    const float* cbias     = (const float*)d_in[6];
    const float* obias     = (const float*)d_in[7];
    float* out = (float*)d_out;

    if (ws_size >= (size_t)WS_NEED) {
        char*  ws         = (char*)d_ws;
        float* block_sums = (float*)(ws + WS_BLOCKSUMS);
        int*   hist       = (int*)  (ws + WS_HIST);
        int*   offs       = (int*)  (ws + WS_OFFS);
        int*   perm       = (int*)  (ws + WS_PERM);
        float* ploss      = (float*)(ws + WS_PLOSS);

        hipMemsetAsync(hist, 0, 4096, stream);
        glove_hist   <<<BATCH / 256, 256, 0, stream>>>(center, hist);
        glove_scan   <<<1, 1024, 0, stream>>>(hist, offs);
        glove_scatter<<<BATCH / 256, 256, 0, stream>>>(center, offs, perm);
        glove_main_perm<<<NBLK, 256, 0, stream>>>(
            perm, center, outside, coocs, weighting, cemb, oemb, cbias, obias, ploss);
        glove_sum    <<<NBLK, 256, 0, stream>>>(ploss, block_sums);
        glove_reduce <<<1, 1024, 0, stream>>>(block_sums, out);
    } else {
        float* block_sums = (float*)d_ws;   // fallback: baseline path, 16 KB
        glove_main  <<<NBLK, 256, 0, stream>>>(
            center, outside, coocs, weighting, cemb, oemb, cbias, obias, block_sums);
        glove_reduce<<<1, 1024, 0, stream>>>(block_sums, out);
    }
}

// Round 2
// 303.349 us; speedup vs baseline: 1.4233x; 1.4233x over previous
//
#include <hip/hip_runtime.h>

#define BATCH 262144
#define EMB 300
#define NBLK 4096
#define WPB 4
// 16 lanes per pair, 4 pair-groups per wave, 4 steps => 16 pairs/wave
// NBLK * WPB * 16 == BATCH

// 4-deep up-front prefetch: all four stages' gathers are issued before the
// first dot product. Data regs = 4 stages x 10 float4 = 160 VGPR; peak ~200.
// __launch_bounds__(256,2): 2 waves/EU floor -> allocator may use up to 256
// VGPR, occupancy cap 2 waves/SIMD = 8 waves/CU, which matches the ~9
// waves/CU the scheduler actually sustains today. The win is per-wave
// memory-level parallelism: ~1 stage in flight -> ~2.5 avg (4 at start).
__global__ __launch_bounds__(256, 2) void glove_main(
    const int*   __restrict__ center,
    const int*   __restrict__ outside,
    const float* __restrict__ coocs,
    const float* __restrict__ weighting,
    const float* __restrict__ cemb,
    const float* __restrict__ oemb,
    const float* __restrict__ cbias,
    const float* __restrict__ obias,
    float*       __restrict__ block_sums)
{
    const int tid  = threadIdx.x;
    const int warp = tid >> 6;
    const int lane = tid & 63;
    const int l    = lane & 15;   // lane within 16-lane pair-group
    const int g    = lane >> 4;   // pair-group 0..3
    const int base = (blockIdx.x * WPB + warp) * 16 + g;

    int ci[4], oi[4];
    #pragma unroll
    for (int it = 0; it < 4; ++it) {
        ci[it] = center[base + it * 4];
        oi[it] = outside[base + it * 4];
    }

    // ---- issue ALL stages' loads up-front ----
    float4 sa[4][5], sb[4][5];
    float  scb[4], sob[4], scc[4], swt[4];

    #pragma unroll
    for (int s = 0; s < 4; ++s) {
        const float4* __restrict__ A = (const float4*)(cemb + (long)ci[s] * EMB);
        const float4* __restrict__ B = (const float4*)(oemb + (long)oi[s] * EMB);
        #pragma unroll
        for (int i = 0; i < 4; ++i) {
            sa[s][i] = A[i * 16 + l];
            sb[s][i] = B[i * 16 + l];
        }
        sa[s][4].x = 0.f; sa[s][4].y = 0.f; sa[s][4].z = 0.f; sa[s][4].w = 0.f;
        sb[s][4] = sa[s][4];
        if (l < 11) {               // 75 float4/row: lanes 0..10 cover [64,75)
            sa[s][4] = A[64 + l];
            sb[s][4] = B[64 + l];
        }
        scb[s] = cbias[ci[s]];
        sob[s] = obias[oi[s]];
        scc[s] = coocs[base + s * 4];
        swt[s] = weighting[base + s * 4];
    }

    float local = 0.0f;

    // ---- compute stages in order; compiler's partial vmcnt waits let
    //      stage it run while stages it+1.. are still in flight ----
    #pragma unroll
    for (int it = 0; it < 4; ++it) {
        float s = 0.f;
        #pragma unroll
        for (int i = 0; i < 5; ++i) {
            s += sa[it][i].x * sb[it][i].x + sa[it][i].y * sb[it][i].y
               + sa[it][i].z * sb[it][i].z + sa[it][i].w * sb[it][i].w;
        }
        const float cbv = scb[it], obv = sob[it], ccv = scc[it], wtv = swt[it];

        // 4-step butterfly within the 16-lane group (masks < 16 stay in-group)
        s += __shfl_xor(s, 1);
        s += __shfl_xor(s, 2);
        s += __shfl_xor(s, 4);
        s += __shfl_xor(s, 8);

        if (l == 0) {
            const float e = s + cbv + obv - ccv;
            local += wtv * e * e;
        }
    }

    // gather the 4 group-leaders (lanes 0,16,32,48) to lane 0
    local += __shfl_down(local, 32, 64);
    local += __shfl_down(local, 16, 64);

    __shared__ float smem[WPB];
    if (lane == 0) smem[warp] = local;
    __syncthreads();
    if (tid == 0)
        block_sums[blockIdx.x] = smem[0] + smem[1] + smem[2] + smem[3];
}

__global__ __launch_bounds__(1024) void glove_reduce(
    const float* __restrict__ part, float* __restrict__ out)
{
    const int t = threadIdx.x;
    float4 v = ((const float4*)part)[t];          // 1024 x 4 = 4096 partials
    float s = v.x + v.y + v.z + v.w;
    #pragma unroll
    for (int off = 32; off > 0; off >>= 1)
        s += __shfl_down(s, off, 64);
    __shared__ float sm[16];
    if ((t & 63) == 0) sm[t >> 6] = s;
    __syncthreads();
    if (t < 16) {
        float x = sm[t];
        #pragma unroll
        for (int off = 8; off > 0; off >>= 1)
            x += __shfl_down(x, off, 16);
        if (t == 0) out[0] = x;
    }
}

extern "C" void kernel_launch(void* const* d_in, const int* in_sizes, int n_in,
                              void* d_out, int out_size, void* d_ws, size_t ws_size,
                              hipStream_t stream) {
    const int*   center    = (const int*)  d_in[0];
    const int*   outside   = (const int*)  d_in[1];
    const float* coocs     = (const float*)d_in[2];
    const float* weighting = (const float*)d_in[3];
    const float* cemb      = (const float*)d_in[4];
    const float* oemb      = (const float*)d_in[5];
    const float* cbias     = (const float*)d_in[6];
    const float* obias     = (const float*)d_in[7];
    float* out        = (float*)d_out;
    float* block_sums = (float*)d_ws;   // NBLK floats = 16 KB, fully overwritten

    glove_main<<<NBLK, 256, 0, stream>>>(
        center, outside, coocs, weighting, cemb, oemb, cbias, obias, block_sums);
    glove_reduce<<<1, 1024, 0, stream>>>(block_sums, out);
}